// Round 14
// baseline (152.552 us; speedup 1.0000x reference)
//
#include <hip/hip_runtime.h>
#include <hip/hip_bf16.h>
#include <math.h>

#define B_ 2
#define T_ 2048
#define E_ 1024
#define H_ 16
#define D_ 64
#define MTOK (B_*T_)   // 4096

typedef __bf16 bf16;
typedef __bf16 bf16x8 __attribute__((ext_vector_type(8)));
typedef __bf16 bf16x4 __attribute__((ext_vector_type(4)));
typedef float  f32x4  __attribute__((ext_vector_type(4)));

__device__ __forceinline__ void gl_lds16(const void* g, void* l) {
    __builtin_amdgcn_global_load_lds(
        (const __attribute__((address_space(1))) void*)g,
        (__attribute__((address_space(3))) void*)l, 16, 0, 0);
}

// ---- vectorized weight transposes: 64x64 tiles, float4 loads, bf16x8 stores ----
// seg 0,1 = split (Wq,Wk); seg 2,3,4 = plain (Wv,Wg,Wo); blocks >=1280 = WaT
__global__ __launch_bounds__(256) void prep_weights_kernel(
    const float* __restrict__ Wq, const float* __restrict__ Wk,
    const float* __restrict__ Wv, const float* __restrict__ Wg,
    const float* __restrict__ Wo, const float* __restrict__ Wa,
    bf16* __restrict__ WTqh, bf16* __restrict__ WTql,
    bf16* __restrict__ WTvg, bf16* __restrict__ WTo,
    float* __restrict__ WaT) {
    const int tid = threadIdx.x;
    if (blockIdx.x >= 1280) {                    // WaT: Wa [1024][16] -> [16][1024]
        int idx = (blockIdx.x - 1280) * 256 + tid;
        WaT[idx] = Wa[(idx & 1023)*H_ + (idx >> 10)];
        return;
    }
    __shared__ float ts[64][65];                 // stride 65: column reads conflict-free
    const int seg = blockIdx.x >> 8;             // 5 segments x 256 tiles
    const int bid = blockIdx.x & 255;
    const float* src = (seg == 0) ? Wq : (seg == 1) ? Wk : (seg == 2) ? Wv
                     : (seg == 3) ? Wg : Wo;
    const int bx = bid & 15, by = bid >> 4;      // 16x16 tiles of 64x64
    {
        const int r = tid >> 2, cb = (tid & 3) * 16;
        const float* s = src + (size_t)(by*64 + r)*1024 + bx*64 + cb;
#pragma unroll
        for (int j = 0; j < 4; ++j) {
            float4 v = *(const float4*)(s + j*4);
            ts[r][cb + j*4 + 0] = v.x; ts[r][cb + j*4 + 1] = v.y;
            ts[r][cb + j*4 + 2] = v.z; ts[r][cb + j*4 + 3] = v.w;
        }
    }
    __syncthreads();
    const int c = tid >> 2, rb = (tid & 3) * 16;
    const size_t obase = (size_t)(bx*64 + c)*1024 + by*64 + rb;
    if (seg < 2) {
        bf16* dh = ((seg == 0) ? WTqh : WTqh + (size_t)1024*1024);
        bf16* dl = ((seg == 0) ? WTql : WTql + (size_t)1024*1024);
#pragma unroll
        for (int half = 0; half < 2; ++half) {
            bf16x8 hv, lv;
#pragma unroll
            for (int e = 0; e < 8; ++e) {
                float v = ts[rb + half*8 + e][c];
                bf16 h = (bf16)v;
                hv[e] = h;
                lv[e] = (bf16)(v - (float)h);
            }
            *(bf16x8*)(dh + obase + half*8) = hv;
            *(bf16x8*)(dl + obase + half*8) = lv;
        }
    } else {
        bf16* dst = (seg == 2) ? WTvg : (seg == 3) ? (WTvg + (size_t)1024*1024) : WTo;
#pragma unroll
        for (int half = 0; half < 2; ++half) {
            bf16x8 hv;
#pragma unroll
            for (int e = 0; e < 8; ++e)
                hv[e] = (bf16)ts[rb + half*8 + e][c];
            *(bf16x8*)(dst + obase + half*8) = hv;
        }
    }
}

// ---- dt -> log(alpha+1e-8) AND x -> xh/xl split (x staged once in LDS) ----
__global__ __launch_bounds__(256) void dtx_kernel(const float* __restrict__ x,
                                                  const float* __restrict__ WaT,
                                                  const float* __restrict__ A_log,
                                                  const float* __restrict__ dt_bias,
                                                  float* __restrict__ lg,
                                                  bf16* __restrict__ xh,
                                                  bf16* __restrict__ xl) {
    __shared__ float xs[16][1032];               // pad 8
    const int tb = blockIdx.x * 16;              // grid 256
    const int tid = threadIdx.x;
#pragma unroll
    for (int v = tid; v < 2048; v += 256) {      // 16 rows x 128 chunks-of-8
        int row = v >> 7, c8 = (v & 127) * 8;
        const float* src = x + (size_t)(tb + row)*E_ + c8;
        float4 a = *(const float4*)src;
        float4 b = *(const float4*)(src + 4);
        float va[8] = {a.x, a.y, a.z, a.w, b.x, b.y, b.z, b.w};
        bf16x8 hv, lv;
#pragma unroll
        for (int j = 0; j < 8; ++j) {
            xs[row][c8+j] = va[j];
            bf16 h = (bf16)va[j];
            hv[j] = h;
            lv[j] = (bf16)(va[j] - (float)h);
        }
        *(bf16x8*)(xh + (size_t)(tb + row)*E_ + c8) = hv;
        *(bf16x8*)(xl + (size_t)(tb + row)*E_ + c8) = lv;
    }
    __syncthreads();
    const int i = tid >> 4, h = tid & 15;
    const float* wrow = WaT + (size_t)h*1024;
    float acc = 0.f;
#pragma unroll 8
    for (int k = 0; k < 1024; k += 4) {
        float4 xv = *(const float4*)&xs[i][k];
        float4 wv = *(const float4*)(wrow + k);
        acc += xv.x*wv.x + xv.y*wv.y + xv.z*wv.z + xv.w*wv.w;
    }
    float z   = acc + dt_bias[h];
    float dtv = (z > 20.f) ? z : log1pf(expf(z));
    float la  = -expf(A_log[h]) * dtv;
    float l   = logf(expf(la) + 1e-8f);
    int n = tb + i;
    int b = n / T_, t = n % T_;
    lg[(size_t)(b*H_ + h)*T_ + t] = l;
}

// ==== fused projection GEMM + (blocks >=512) f64 scan of lg -> cl ====
__global__ __launch_bounds__(256, 2) void gemm_qkvg_kernel(
    const bf16* __restrict__ Ah, const bf16* __restrict__ Al,
    const bf16* __restrict__ Bh, const bf16* __restrict__ Bl,
    const bf16* __restrict__ BTvg,
    bf16* __restrict__ qhb, bf16* __restrict__ qlb,
    bf16* __restrict__ khb, bf16* __restrict__ klb,
    bf16* __restrict__ vt, bf16* __restrict__ Gf,
    const float* __restrict__ lg, double* __restrict__ cl) {
    const int K = E_;
    __shared__ __align__(16) bf16 S[5][128*32];
    const int tid = threadIdx.x, lane = tid & 63, wid = tid >> 6;
    if (blockIdx.x >= 512) {
        // ---------------- scan branch (32 blocks): f64 inclusive scan ----------------
        double* ls = (double*)&S[0][0];
        int row = blockIdx.x - 512;
        const float* p = lg + (size_t)row*T_ + tid*8;
        double loc[8], s = 0.0;
#pragma unroll
        for (int j = 0; j < 8; ++j) { s += (double)p[j]; loc[j] = s; }
        ls[tid] = s;
        __syncthreads();
        for (int off = 1; off < 256; off <<= 1) {
            double add = (tid >= off) ? ls[tid - off] : 0.0;
            __syncthreads();
            ls[tid] += add;
            __syncthreads();
        }
        double prefix = ls[tid] - s;
        double* o = cl + (size_t)row*T_ + tid*8;
#pragma unroll
        for (int j = 0; j < 8; ++j) o[j] = prefix + loc[j];
        return;
    }
    const int wr = wid >> 1, wc = wid & 1;
    const int lr = lane & 15, lg4 = lane >> 4;
    const int tr = tid >> 2;
    const int tc = ((tid & 3) ^ ((tid >> 3) & 3)) * 8;   // pre-swizzled src chunk
    const int co = (lg4 ^ ((lr >> 1) & 3)) * 8;          // swizzled read chunk
    int bid = blockIdx.x;
    bid = (bid & 7) * 64 + (bid >> 3);                   // XCD swizzle, 512 blocks
    const int bx = bid & 15, by = bid >> 4;              // 16 N-panels x 32 M-panels
    f32x4 accq[4][4], accv[4][4];
#pragma unroll
    for (int m = 0; m < 4; ++m)
#pragma unroll
        for (int n = 0; n < 4; ++n) { accq[m][n] = (f32x4)0.0f; accv[m][n] = (f32x4)0.0f; }
    for (int k0 = 0; k0 < K; k0 += 32) {
#pragma unroll
        for (int i = 0; i < 2; ++i) {
            size_t ga = (size_t)(by*128 + i*64 + tr)*K + k0 + tc;
            size_t gb = (size_t)(bx*128 + i*64 + tr)*K + k0 + tc;
            gl_lds16(Ah   + ga, &S[0][(i*256 + wid*64)*8]);
            gl_lds16(Al   + ga, &S[1][(i*256 + wid*64)*8]);
            gl_lds16(Bh   + gb, &S[2][(i*256 + wid*64)*8]);
            gl_lds16(Bl   + gb, &S[3][(i*256 + wid*64)*8]);
            gl_lds16(BTvg + gb, &S[4][(i*256 + wid*64)*8]);
        }
        __syncthreads();
        bf16x8 ah[4], al[4], bh[4], bl[4], bv[4];
#pragma unroll
        for (int m = 0; m < 4; ++m) {
            int o = (wr*64 + m*16 + lr)*32 + co;
            ah[m] = *(const bf16x8*)&S[0][o];
            al[m] = *(const bf16x8*)&S[1][o];
        }
#pragma unroll
        for (int n = 0; n < 4; ++n) {
            int o = (wc*64 + n*16 + lr)*32 + co;
            bh[n] = *(const bf16x8*)&S[2][o];
            bl[n] = *(const bf16x8*)&S[3][o];
            bv[n] = *(const bf16x8*)&S[4][o];
        }
#pragma unroll
        for (int m = 0; m < 4; ++m)
#pragma unroll
            for (int n = 0; n < 4; ++n) {
                accq[m][n] = __builtin_amdgcn_mfma_f32_16x16x32_bf16(al[m], bh[n], accq[m][n], 0, 0, 0);
                accq[m][n] = __builtin_amdgcn_mfma_f32_16x16x32_bf16(ah[m], bl[n], accq[m][n], 0, 0, 0);
                accq[m][n] = __builtin_amdgcn_mfma_f32_16x16x32_bf16(ah[m], bh[n], accq[m][n], 0, 0, 0);
                accv[m][n] = __builtin_amdgcn_mfma_f32_16x16x32_bf16(ah[m], bv[n], accv[m][n], 0, 0, 0);
            }
        __syncthreads();
    }
    // ---------------- qk epilogue: L2-norm + hi/lo split ----------------
    {
        const int headg = bx*2 + wc;                 // 0..31
        bf16* dh = (headg < 16) ? qhb : khb;
        bf16* dl = (headg < 16) ? qlb : klb;
        const int h = headg & 15;
#pragma unroll
        for (int m = 0; m < 4; ++m)
#pragma unroll
            for (int r = 0; r < 4; ++r) {
                float ss = accq[m][0][r]*accq[m][0][r] + accq[m][1][r]*accq[m][1][r]
                         + accq[m][2][r]*accq[m][2][r] + accq[m][3][r]*accq[m][3][r];
#pragma unroll
                for (int off = 1; off < 16; off <<= 1) ss += __shfl_xor(ss, off, 64);
                float sc = 1.0f / fmaxf(sqrtf(ss), 1e-12f);
                int token = by*128 + wr*64 + m*16 + lg4*4 + r;
#pragma unroll
                for (int n = 0; n < 4; ++n) {
                    int d = n*16 + lr;
                    float qv = accq[m][n][r] * sc;
                    bf16 hv = (bf16)qv;
                    size_t idx = ((size_t)token*H_ + h)*64 + d;
                    dh[idx] = hv;
                    dl[idx] = (bf16)(qv - (float)hv);
                }
            }
    }
    // ---------------- vg epilogue: transposed-V / silu-G (bf16 gate) ----------------
    {
        const int colbase = bx*128 + wc*64;
        const int b = by >> 4;
        if (colbase < 1024) {
            const int head = colbase >> 6;
#pragma unroll
            for (int m = 0; m < 4; ++m) {
                int trow = by*128 + wr*64 + m*16 + lg4*4;
                int tloc = trow - b*T_;
#pragma unroll
                for (int n = 0; n < 4; ++n) {
                    int d = n*16 + lr;
                    bf16x4 pk;
                    pk[0] = (bf16)accv[m][n][0]; pk[1] = (bf16)accv[m][n][1];
                    pk[2] = (bf16)accv[m][n][2]; pk[3] = (bf16)accv[m][n][3];
                    *(bf16x4*)(vt + ((size_t)((b*H_ + head)*64 + d))*T_ + tloc) = pk;
                }
            }
        } else {
#pragma unroll
            for (int m = 0; m < 4; ++m)
#pragma unroll
                for (int r = 0; r < 4; ++r) {
                    int token = by*128 + wr*64 + m*16 + lg4*4 + r;
#pragma unroll
                    for (int n = 0; n < 4; ++n) {
                        int colg = colbase - 1024 + n*16 + lr;
                        float g = accv[m][n][r];
                        Gf[(size_t)token*E_ + colg] = (bf16)(g / (1.0f + __expf(-g)));
                    }
                }
        }
    }
}

// ---- output GEMM: out f32 = Yb bf16 @ WoT, 128x64 tile, BK=64, swizzled LDS ----
__global__ __launch_bounds__(256) void gemm_out_kernel(
    const bf16* __restrict__ A, const bf16* __restrict__ BT, float* __restrict__ C) {
    const int K = E_, N = E_;
    __shared__ __align__(16) bf16 As[128*64];    // 16 KB
    __shared__ __align__(16) bf16 Bs[64*64];     // 8 KB
    int bid = blockIdx.x;
    bid = (bid & 7) * 64 + (bid >> 3);           // XCD swizzle, 512 blocks
    const int bx = bid & 15, by = bid >> 4;      // nbx = 1024/64 = 16
    const int tid = threadIdx.x, lane = tid & 63, wid = tid >> 6;
    const int wr = wid >> 1, wc = wid & 1;       // waves 64x32
    const int lr = lane & 15, lg4 = lane >> 4;
    f32x4 acc[4][2];
#pragma unroll
    for (int m = 0; m < 4; ++m)
#pragma unroll
        for (int n = 0; n < 2; ++n) acc[m][n] = (f32x4)0.0f;
    const int srow = lane >> 3;                  // 0..7
    const int csrc = ((lane & 7) ^ srow) * 8;    // pre-swizzled source elems
    for (int k0 = 0; k0 < K; k0 += 64) {
#pragma unroll
        for (int i = 0; i < 4; ++i)
            gl_lds16(A + (size_t)(by*128 + i*32 + wid*8 + srow)*K + k0 + csrc,
                     &As[(i*32 + wid*8)*64]);
#pragma unroll
        for (int j = 0; j < 2; ++j)
            gl_lds16(BT + (size_t)(bx*64 + j*32 + wid*8 + srow)*K + k0 + csrc,
                     &Bs[(j*32 + wid*8)*64]);
        __syncthreads();
        bf16x8 af[4][2], bfr[2][2];
#pragma unroll
        for (int m = 0; m < 4; ++m) {
            int row = wr*64 + m*16 + lr;         // row&7 == lr&7
#pragma unroll
            for (int kk = 0; kk < 2; ++kk)
                af[m][kk] = *(const bf16x8*)&As[row*64 + (((kk*4 + lg4) ^ (lr & 7))*8)];
        }
#pragma unroll
        for (int n = 0; n < 2; ++n) {
            int row = wc*32 + n*16 + lr;         // row&7 == lr&7
#pragma unroll
            for (int kk = 0; kk < 2; ++kk)
                bfr[n][kk] = *(const bf16x8*)&Bs[row*64 + (((kk*4 + lg4) ^ (lr & 7))*8)];
        }
#pragma unroll
        for (int m = 0; m < 4; ++m)
#pragma unroll
            for (int n = 0; n < 2; ++n) {
                acc[m][n] = __builtin_amdgcn_mfma_f32_16x16x32_bf16(af[m][0], bfr[n][0], acc[m][n], 0, 0, 0);
                acc[m][n] = __builtin_amdgcn_mfma_f32_16x16x32_bf16(af[m][1], bfr[n][1], acc[m][n], 0, 0, 0);
            }
        __syncthreads();
    }
    const int crow = by*128 + wr*64;
    const int ccol = bx*64 + wc*32 + lr;
#pragma unroll
    for (int m = 0; m < 4; ++m)
#pragma unroll
        for (int r = 0; r < 4; ++r) {
            int row = crow + m*16 + lg4*4 + r;
#pragma unroll
            for (int n = 0; n < 2; ++n)
                C[(size_t)row*N + ccol + n*16] = acc[m][n][r];
        }
}

// ---- decay attention: QBLK=128, dbuf prefetch, decay-reach jt skip ----
__global__ __launch_bounds__(256) void attn_kernel(
    const bf16* __restrict__ qh, const bf16* __restrict__ ql,
    const bf16* __restrict__ kh, const bf16* __restrict__ kl,
    const bf16* __restrict__ vt, const double* __restrict__ cl,
    const bf16* __restrict__ Gf, const float* __restrict__ rms_w,
    bf16* __restrict__ Y) {
    __shared__ __align__(16) bf16 Ksh[2][64*64];  // [key][d] swizzled, ping-pong
    __shared__ __align__(16) bf16 Ksl[2][64*64];
    __shared__ __align__(16) bf16 Vs[2][64*64];   // [d][key] swizzled, ping-pong
    __shared__ __align__(16) bf16 Ps[128*64];     // [qrow][key] swizzled
    const int rank = blockIdx.x >> 5, bh = blockIdx.x & 31;
    const int it = (rank < 8) ? (15 - rank) : (rank - 8);
    const int b = bh >> 4, h = bh & 15;
    const int tid = threadIdx.x, lane = tid & 63, wid = tid >> 6;
    const int i0 = it * 128;
    const int lr = lane & 15, lg4 = lane >> 4;
    bf16x8 qfh[2][2], qfl[2][2];
#pragma unroll
    for (int mm = 0; mm < 2; ++mm) {
        int qtok = i0 + wid*32 + mm*16 + lr;
        size_t qa = (size_t)(b*T_ + qtok)*E_ + h*64 + lg4*8;
        qfh[mm][0] = *(const bf16x8*)(qh + qa);
        qfh[mm][1] = *(const bf16x8*)(qh + qa + 32);
        qfl[mm][0] = *(const bf16x8*)(ql + qa);
        qfl[mm][1] = *(const bf16x8*)(ql + qa + 32);
    }
    const double* clrow = cl + (size_t)bh*T_;
    const double base = clrow[i0];
    float cli2[2][4];
#pragma unroll
    for (int mm = 0; mm < 2; ++mm)
#pragma unroll
        for (int r = 0; r < 4; ++r)
            cli2[mm][r] = (float)(clrow[i0 + wid*32 + mm*16 + lg4*4 + r] - base);
    f32x4 oacc[2][4];
#pragma unroll
    for (int mm = 0; mm < 2; ++mm)
#pragma unroll
        for (int n = 0; n < 4; ++n) oacc[mm][n] = (f32x4)0.0f;
    const int srow8 = lane >> 3;
    const int csrc  = (lane & 7) ^ srow8;
    auto STAGE = [&](int jt, int buf) {
        const int j0 = jt * 64;
#pragma unroll
        for (int i = 0; i < 2; ++i) {
            int krow = j0 + i*32 + wid*8 + srow8;
            int drow = i*32 + wid*8 + srow8;
            size_t gk = (size_t)(b*T_ + krow)*E_ + h*64 + csrc*8;
            gl_lds16(kh + gk, &Ksh[buf][(i*32 + wid*8)*64]);
            gl_lds16(kl + gk, &Ksl[buf][(i*32 + wid*8)*64]);
            gl_lds16(vt + (size_t)(bh*64 + drow)*T_ + j0 + csrc*8, &Vs[buf][(i*32 + wid*8)*64]);
        }
    };
    const int niter = 2*it + 2;
    int jt_min;
    {
        int lo = 0, hi = niter - 1;
        while (lo < hi) {
            int mid = (lo + hi) >> 1;
            int jend = mid*64 + 63; if (jend > i0) jend = i0;
            if (clrow[jend] <= base + 95.0) hi = mid; else lo = mid + 1;
        }
        jt_min = lo;
    }
    STAGE(jt_min, 0);
    __syncthreads();
    int cur = 0;
    for (int jt = jt_min; jt < niter; ++jt) {
        const int j0 = jt * 64;
        if (jt + 1 < niter) STAGE(jt + 1, cur ^ 1);
#pragma unroll
        for (int n = 0; n < 4; ++n) {
            const int r = n*16 + lr;
            const int sw = r & 7;
            const int ko = r*64;
            bf16x8 k_h0 = *(const bf16x8*)&Ksh[cur][ko + ((lg4 ^ sw)*8)];
            bf16x8 k_h1 = *(const bf16x8*)&Ksh[cur][ko + (((lg4+4) ^ sw)*8)];
            bf16x8 k_l0 = *(const bf16x8*)&Ksl[cur][ko + ((lg4 ^ sw)*8)];
            bf16x8 k_l1 = *(const bf16x8*)&Ksl[cur][ko + (((lg4+4) ^ sw)*8)];
            const int j = j0 + r;
            const float cj = (float)(clrow[j] - base);
#pragma unroll
            for (int mm = 0; mm < 2; ++mm) {
                f32x4 s = (f32x4)0.0f;
                __builtin_amdgcn_s_setprio(1);
                s = __builtin_amdgcn_mfma_f32_16x16x32_bf16(qfl[mm][0], k_h0, s, 0, 0, 0);
                s = __builtin_amdgcn_mfma_f32_16x16x32_bf16(qfl[mm][1], k_h1, s, 0, 0, 0);
                s = __builtin_amdgcn_mfma_f32_16x16x32_bf16(qfh[mm][0], k_l0, s, 0, 0, 0);
                s = __builtin_amdgcn_mfma_f32_16x16x32_bf16(qfh[mm][1], k_l1, s, 0, 0, 0);
                s = __builtin_amdgcn_mfma_f32_16x16x32_bf16(qfh[mm][0], k_h0, s, 0, 0, 0);
                s = __builtin_amdgcn_mfma_f32_16x16x32_bf16(qfh[mm][1], k_h1, s, 0, 0, 0);
                __builtin_amdgcn_s_setprio(0);
                const int prbase = wid*32 + mm*16 + lg4*4;
#pragma unroll
                for (int r4 = 0; r4 < 4; ++r4) {
                    const int pr = prbase + r4;
                    const int qrow = i0 + pr;
                    float val = (j <= qrow)
                        ? s[r4] * __expf(cli2[mm][r4] - cj) : 0.0f;
                    const int cw = n*2 + (lr >> 3);
                    Ps[pr*64 + ((cw ^ (pr & 7))*8) + (lane & 7)] = (bf16)val;
                }
            }
        }
#pragma unroll
        for (int kk = 0; kk < 2; ++kk) {
            const int js = kk*4 + lg4;
            bf16x8 pf[2];
#pragma unroll
            for (int mm = 0; mm < 2; ++mm) {
                const int rp = wid*32 + mm*16 + lr;
                pf[mm] = *(const bf16x8*)&Ps[rp*64 + ((js ^ (rp & 7))*8)];
            }
            __builtin_amdgcn_s_setprio(1);
#pragma unroll
            for (int n = 0; n < 4; ++n) {
                const int rv = n*16 + lr;
                bf16x8 vf = *(const bf16x8*)&Vs[cur][rv*64 + ((js ^ (rv & 7))*8)];
                oacc[0][n] = __builtin_amdgcn_mfma_f32_16x16x32_bf16(pf[0], vf, oacc[0][n], 0, 0, 0);
                oacc[1][n] = __builtin_amdgcn_mfma_f32_16x16x32_bf16(pf[1], vf, oacc[1][n], 0, 0, 0);
            }
            __builtin_amdgcn_s_setprio(0);
        }
        __syncthreads();
        cur ^= 1;
    }
#pragma unroll
    for (int mm = 0; mm < 2; ++mm)
#pragma unroll
        for (int r = 0; r < 4; ++r) {
            float ss = oacc[mm][0][r]*oacc[mm][0][r] + oacc[mm][1][r]*oacc[mm][1][r]
                     + oacc[mm][2][r]*oacc[mm][2][r] + oacc[mm][3][r]*oacc[mm][3][r];
#pragma unroll
            for (int off = 1; off < 16; off <<= 1) ss += __shfl_xor(ss, off, 64);
            const float scale = rsqrtf(ss * (1.0f/64.0f) + 1e-6f);
            const int gtok = b*T_ + i0 + wid*32 + mm*16 + lg4*4 + r;
#pragma unroll
            for (int n = 0; n < 4; ++n) {
                const int d = n*16 + lr;
                float o = oacc[mm][n][r] * scale * rms_w[d];
                float gate = (float)Gf[(size_t)gtok*E_ + h*64 + d];
                Y[(size_t)gtok*E_ + h*64 + d] = (bf16)(o * gate);
            }
        }
}

extern "C" void kernel_launch(void* const* d_in, const int* in_sizes, int n_in,
                              void* d_out, int out_size, void* d_ws, size_t ws_size,
                              hipStream_t stream) {
    const float* x       = (const float*)d_in[0];
    const float* Wq      = (const float*)d_in[1];
    const float* Wk      = (const float*)d_in[2];
    const float* Wv      = (const float*)d_in[3];
    const float* Wa      = (const float*)d_in[4];
    const float* Wg      = (const float*)d_in[5];
    const float* Wo      = (const float*)d_in[6];
    const float* A_log   = (const float*)d_in[7];
    const float* dt_bias = (const float*)d_in[8];
    const float* rms_w   = (const float*)d_in[9];
    float* out = (float*)d_out;

    char* w = (char*)d_ws;
    size_t off = 0;
    auto alloc = [&](size_t bytes) {
        void* p = w + off; off += (bytes + 255) & ~(size_t)255; return p;
    };
    bf16*   xh   = (bf16*)  alloc((size_t)MTOK*E_*2);
    bf16*   xl   = (bf16*)  alloc((size_t)MTOK*E_*2);
    bf16*   WTqh = (bf16*)  alloc((size_t)2048*E_*2);
    bf16*   WTql = (bf16*)  alloc((size_t)2048*E_*2);
    bf16*   WTvg = (bf16*)  alloc((size_t)2048*E_*2);
    bf16*   WTo  = (bf16*)  alloc((size_t)E_*E_*2);
    bf16*   qhb  = (bf16*)  alloc((size_t)MTOK*E_*2);
    bf16*   qlb  = (bf16*)  alloc((size_t)MTOK*E_*2);
    bf16*   khb  = (bf16*)  alloc((size_t)MTOK*E_*2);
    bf16*   klb  = (bf16*)  alloc((size_t)MTOK*E_*2);
    bf16*   vt   = (bf16*)  alloc((size_t)MTOK*E_*2);
    bf16*   Gf   = (bf16*)  alloc((size_t)MTOK*E_*2);
    float*  lg   = (float*) alloc((size_t)B_*H_*T_*4);
    double* cl   = (double*)alloc((size_t)B_*H_*T_*8);
    bf16*   Yb   = (bf16*)  alloc((size_t)MTOK*E_*2);
    float*  WaT  = (float*) alloc((size_t)H_*E_*4);

    // weight prep (vectorized; incl. WaT as trailing blocks)
    hipLaunchKernelGGL(prep_weights_kernel, dim3(1344), dim3(256), 0, stream,
                       Wq, Wk, Wv, Wg, Wo, Wa, WTqh, WTql, WTvg, WTo, WaT);

    hipLaunchKernelGGL(dtx_kernel, dim3(256), dim3(256), 0, stream,
                       x, WaT, A_log, dt_bias, lg, xh, xl);

    // fused projection GEMMs + scan (blocks >=512)
    hipLaunchKernelGGL(gemm_qkvg_kernel, dim3(544), dim3(256), 0, stream,
                       xh, xl, WTqh, WTql, WTvg, qhb, qlb, khb, klb, vt, Gf, lg, cl);

    // attention + RMSNorm + gate
    hipLaunchKernelGGL(attn_kernel, dim3(512), dim3(256), 0, stream,
                       qhb, qlb, khb, klb, vt, cl, Gf, rms_w, Yb);

    // output projection (BK=64)
    hipLaunchKernelGGL(gemm_out_kernel, dim3(512), dim3(256), 0, stream, Yb, WTo, out);
}

// Round 15
// 138.937 us; speedup vs baseline: 1.0980x; 1.0980x over previous
//
#include <hip/hip_runtime.h>
#include <hip/hip_bf16.h>
#include <math.h>

#define B_ 2
#define T_ 2048
#define E_ 1024
#define H_ 16
#define D_ 64
#define MTOK (B_*T_)   // 4096

typedef __bf16 bf16;
typedef __bf16 bf16x8 __attribute__((ext_vector_type(8)));
typedef __bf16 bf16x4 __attribute__((ext_vector_type(4)));
typedef float  f32x4  __attribute__((ext_vector_type(4)));

__device__ __forceinline__ void gl_lds16(const void* g, void* l) {
    __builtin_amdgcn_global_load_lds(
        (const __attribute__((address_space(1))) void*)g,
        (__attribute__((address_space(3))) void*)l, 16, 0, 0);
}

// ==== merged prep: blocks 0-1279 = weight transposes; 1280-1535 = dt+x-split ====
__global__ __launch_bounds__(256) void prep_dtx_kernel(
    const float* __restrict__ Wq, const float* __restrict__ Wk,
    const float* __restrict__ Wv, const float* __restrict__ Wg,
    const float* __restrict__ Wo, const float* __restrict__ Wa,
    const float* __restrict__ x, const float* __restrict__ A_log,
    const float* __restrict__ dt_bias,
    bf16* __restrict__ WTqh, bf16* __restrict__ WTql,
    bf16* __restrict__ WTvg, bf16* __restrict__ WTo,
    float* __restrict__ lg, bf16* __restrict__ xh, bf16* __restrict__ xl) {
    __shared__ __align__(16) float lds_raw[16 * 1032];   // 66048 B, shared by branches
    const int tid = threadIdx.x;
    if (blockIdx.x < 1280) {
        // ---------------- weight transpose branch ----------------
        float (*ts)[65] = (float (*)[65])lds_raw;        // 64x65 = 16.6 KB
        const int seg = blockIdx.x >> 8;                 // 5 segments x 256 tiles
        const int bid = blockIdx.x & 255;
        const float* src = (seg == 0) ? Wq : (seg == 1) ? Wk : (seg == 2) ? Wv
                         : (seg == 3) ? Wg : Wo;
        const int bx = bid & 15, by = bid >> 4;          // 16x16 tiles of 64x64
        {
            const int r = tid >> 2, cb = (tid & 3) * 16;
            const float* s = src + (size_t)(by*64 + r)*1024 + bx*64 + cb;
#pragma unroll
            for (int j = 0; j < 4; ++j) {
                float4 v = *(const float4*)(s + j*4);
                ts[r][cb + j*4 + 0] = v.x; ts[r][cb + j*4 + 1] = v.y;
                ts[r][cb + j*4 + 2] = v.z; ts[r][cb + j*4 + 3] = v.w;
            }
        }
        __syncthreads();
        const int c = tid >> 2, rb = (tid & 3) * 16;
        const size_t obase = (size_t)(bx*64 + c)*1024 + by*64 + rb;
        if (seg < 2) {
            bf16* dh = ((seg == 0) ? WTqh : WTqh + (size_t)1024*1024);
            bf16* dl = ((seg == 0) ? WTql : WTql + (size_t)1024*1024);
#pragma unroll
            for (int half = 0; half < 2; ++half) {
                bf16x8 hv, lv;
#pragma unroll
                for (int e = 0; e < 8; ++e) {
                    float v = ts[rb + half*8 + e][c];
                    bf16 h = (bf16)v;
                    hv[e] = h;
                    lv[e] = (bf16)(v - (float)h);
                }
                *(bf16x8*)(dh + obase + half*8) = hv;
                *(bf16x8*)(dl + obase + half*8) = lv;
            }
        } else {
            bf16* dst = (seg == 2) ? WTvg : (seg == 3) ? (WTvg + (size_t)1024*1024) : WTo;
#pragma unroll
            for (int half = 0; half < 2; ++half) {
                bf16x8 hv;
#pragma unroll
                for (int e = 0; e < 8; ++e)
                    hv[e] = (bf16)ts[rb + half*8 + e][c];
                *(bf16x8*)(dst + obase + half*8) = hv;
            }
        }
    } else {
        // ---------------- dt + x-split branch ----------------
        float (*wt)[1032] = (float (*)[1032])lds_raw;    // Wa^T [16][1032]
        const int tb = (blockIdx.x - 1280) * 16;         // 256 blocks x 16 tokens
        // (a) stage Wa [1024][16] -> LDS transposed
#pragma unroll
        for (int v = tid; v < 4096; v += 256) {          // 4096 float4s
            int k = v >> 2, h4 = (v & 3) * 4;
            float4 wv = *(const float4*)(Wa + (size_t)k*H_ + h4);
            wt[h4+0][k] = wv.x; wt[h4+1][k] = wv.y;
            wt[h4+2][k] = wv.z; wt[h4+3][k] = wv.w;
        }
        // (b) x -> bf16 hi/lo split (global->global, no LDS)
#pragma unroll
        for (int v = tid; v < 2048; v += 256) {          // 16 rows x 128 chunks-of-8
            int row = v >> 7, c8 = (v & 127) * 8;
            const float* src = x + (size_t)(tb + row)*E_ + c8;
            float4 a = *(const float4*)src;
            float4 b = *(const float4*)(src + 4);
            float va[8] = {a.x, a.y, a.z, a.w, b.x, b.y, b.z, b.w};
            bf16x8 hv, lv;
#pragma unroll
            for (int j = 0; j < 8; ++j) {
                bf16 h = (bf16)va[j];
                hv[j] = h;
                lv[j] = (bf16)(va[j] - (float)h);
            }
            *(bf16x8*)(xh + (size_t)(tb + row)*E_ + c8) = hv;
            *(bf16x8*)(xl + (size_t)(tb + row)*E_ + c8) = lv;
        }
        __syncthreads();
        // (c) dot: thread (token i, head h); x row broadcast across 16 h-lanes
        const int i = tid >> 4, h = tid & 15;
        const float* xrow = x + (size_t)(tb + i)*E_;
        float acc = 0.f;
#pragma unroll 8
        for (int k = 0; k < 1024; k += 4) {
            float4 xv = *(const float4*)(xrow + k);
            float4 wv = *(const float4*)&wt[h][k];
            acc += xv.x*wv.x + xv.y*wv.y + xv.z*wv.z + xv.w*wv.w;
        }
        float z   = acc + dt_bias[h];
        float dtv = (z > 20.f) ? z : log1pf(expf(z));
        float la  = -expf(A_log[h]) * dtv;
        float l   = logf(expf(la) + 1e-8f);
        int n = tb + i;
        int b = n / T_, t = n % T_;
        lg[(size_t)(b*H_ + h)*T_ + t] = l;
    }
}

// ==== fused projection GEMM + (blocks >=512) f64 scan of lg -> cl ====
__global__ __launch_bounds__(256, 2) void gemm_qkvg_kernel(
    const bf16* __restrict__ Ah, const bf16* __restrict__ Al,
    const bf16* __restrict__ Bh, const bf16* __restrict__ Bl,
    const bf16* __restrict__ BTvg,
    bf16* __restrict__ qhb, bf16* __restrict__ qlb,
    bf16* __restrict__ khb, bf16* __restrict__ klb,
    bf16* __restrict__ vt, bf16* __restrict__ Gf,
    const float* __restrict__ lg, double* __restrict__ cl) {
    const int K = E_;
    __shared__ __align__(16) bf16 S[5][128*32];
    const int tid = threadIdx.x, lane = tid & 63, wid = tid >> 6;
    if (blockIdx.x >= 512) {
        // ---------------- scan branch (32 blocks): f64 inclusive scan ----------------
        double* ls = (double*)&S[0][0];
        int row = blockIdx.x - 512;
        const float* p = lg + (size_t)row*T_ + tid*8;
        double loc[8], s = 0.0;
#pragma unroll
        for (int j = 0; j < 8; ++j) { s += (double)p[j]; loc[j] = s; }
        ls[tid] = s;
        __syncthreads();
        for (int off = 1; off < 256; off <<= 1) {
            double add = (tid >= off) ? ls[tid - off] : 0.0;
            __syncthreads();
            ls[tid] += add;
            __syncthreads();
        }
        double prefix = ls[tid] - s;
        double* o = cl + (size_t)row*T_ + tid*8;
#pragma unroll
        for (int j = 0; j < 8; ++j) o[j] = prefix + loc[j];
        return;
    }
    const int wr = wid >> 1, wc = wid & 1;
    const int lr = lane & 15, lg4 = lane >> 4;
    const int tr = tid >> 2;
    const int tc = ((tid & 3) ^ ((tid >> 3) & 3)) * 8;   // pre-swizzled src chunk
    const int co = (lg4 ^ ((lr >> 1) & 3)) * 8;          // swizzled read chunk
    int bid = blockIdx.x;
    bid = (bid & 7) * 64 + (bid >> 3);                   // XCD swizzle, 512 blocks
    const int bx = bid & 15, by = bid >> 4;              // 16 N-panels x 32 M-panels
    f32x4 accq[4][4], accv[4][4];
#pragma unroll
    for (int m = 0; m < 4; ++m)
#pragma unroll
        for (int n = 0; n < 4; ++n) { accq[m][n] = (f32x4)0.0f; accv[m][n] = (f32x4)0.0f; }
    for (int k0 = 0; k0 < K; k0 += 32) {
#pragma unroll
        for (int i = 0; i < 2; ++i) {
            size_t ga = (size_t)(by*128 + i*64 + tr)*K + k0 + tc;
            size_t gb = (size_t)(bx*128 + i*64 + tr)*K + k0 + tc;
            gl_lds16(Ah   + ga, &S[0][(i*256 + wid*64)*8]);
            gl_lds16(Al   + ga, &S[1][(i*256 + wid*64)*8]);
            gl_lds16(Bh   + gb, &S[2][(i*256 + wid*64)*8]);
            gl_lds16(Bl   + gb, &S[3][(i*256 + wid*64)*8]);
            gl_lds16(BTvg + gb, &S[4][(i*256 + wid*64)*8]);
        }
        __syncthreads();
        bf16x8 ah[4], al[4], bh[4], bl[4], bv[4];
#pragma unroll
        for (int m = 0; m < 4; ++m) {
            int o = (wr*64 + m*16 + lr)*32 + co;
            ah[m] = *(const bf16x8*)&S[0][o];
            al[m] = *(const bf16x8*)&S[1][o];
        }
#pragma unroll
        for (int n = 0; n < 4; ++n) {
            int o = (wc*64 + n*16 + lr)*32 + co;
            bh[n] = *(const bf16x8*)&S[2][o];
            bl[n] = *(const bf16x8*)&S[3][o];
            bv[n] = *(const bf16x8*)&S[4][o];
        }
#pragma unroll
        for (int m = 0; m < 4; ++m)
#pragma unroll
            for (int n = 0; n < 4; ++n) {
                accq[m][n] = __builtin_amdgcn_mfma_f32_16x16x32_bf16(al[m], bh[n], accq[m][n], 0, 0, 0);
                accq[m][n] = __builtin_amdgcn_mfma_f32_16x16x32_bf16(ah[m], bl[n], accq[m][n], 0, 0, 0);
                accq[m][n] = __builtin_amdgcn_mfma_f32_16x16x32_bf16(ah[m], bh[n], accq[m][n], 0, 0, 0);
                accv[m][n] = __builtin_amdgcn_mfma_f32_16x16x32_bf16(ah[m], bv[n], accv[m][n], 0, 0, 0);
            }
        __syncthreads();
    }
    // ---------------- qk epilogue: L2-norm + hi/lo split ----------------
    {
        const int headg = bx*2 + wc;                 // 0..31
        bf16* dh = (headg < 16) ? qhb : khb;
        bf16* dl = (headg < 16) ? qlb : klb;
        const int h = headg & 15;
#pragma unroll
        for (int m = 0; m < 4; ++m)
#pragma unroll
            for (int r = 0; r < 4; ++r) {
                float ss = accq[m][0][r]*accq[m][0][r] + accq[m][1][r]*accq[m][1][r]
                         + accq[m][2][r]*accq[m][2][r] + accq[m][3][r]*accq[m][3][r];
#pragma unroll
                for (int off = 1; off < 16; off <<= 1) ss += __shfl_xor(ss, off, 64);
                float sc = 1.0f / fmaxf(sqrtf(ss), 1e-12f);
                int token = by*128 + wr*64 + m*16 + lg4*4 + r;
#pragma unroll
                for (int n = 0; n < 4; ++n) {
                    int d = n*16 + lr;
                    float qv = accq[m][n][r] * sc;
                    bf16 hv = (bf16)qv;
                    size_t idx = ((size_t)token*H_ + h)*64 + d;
                    dh[idx] = hv;
                    dl[idx] = (bf16)(qv - (float)hv);
                }
            }
    }
    // ---------------- vg epilogue: transposed-V / silu-G (bf16 gate) ----------------
    {
        const int colbase = bx*128 + wc*64;
        const int b = by >> 4;
        if (colbase < 1024) {
            const int head = colbase >> 6;
#pragma unroll
            for (int m = 0; m < 4; ++m) {
                int trow = by*128 + wr*64 + m*16 + lg4*4;
                int tloc = trow - b*T_;
#pragma unroll
                for (int n = 0; n < 4; ++n) {
                    int d = n*16 + lr;
                    bf16x4 pk;
                    pk[0] = (bf16)accv[m][n][0]; pk[1] = (bf16)accv[m][n][1];
                    pk[2] = (bf16)accv[m][n][2]; pk[3] = (bf16)accv[m][n][3];
                    *(bf16x4*)(vt + ((size_t)((b*H_ + head)*64 + d))*T_ + tloc) = pk;
                }
            }
        } else {
#pragma unroll
            for (int m = 0; m < 4; ++m)
#pragma unroll
                for (int r = 0; r < 4; ++r) {
                    int token = by*128 + wr*64 + m*16 + lg4*4 + r;
#pragma unroll
                    for (int n = 0; n < 4; ++n) {
                        int colg = colbase - 1024 + n*16 + lr;
                        float g = accv[m][n][r];
                        Gf[(size_t)token*E_ + colg] = (bf16)(g / (1.0f + __expf(-g)));
                    }
                }
        }
    }
}

// ---- output GEMM: out f32 = Yb bf16 @ WoT, 128x64 tile, BK=64, swizzled LDS ----
__global__ __launch_bounds__(256) void gemm_out_kernel(
    const bf16* __restrict__ A, const bf16* __restrict__ BT, float* __restrict__ C) {
    const int K = E_, N = E_;
    __shared__ __align__(16) bf16 As[128*64];    // 16 KB
    __shared__ __align__(16) bf16 Bs[64*64];     // 8 KB
    int bid = blockIdx.x;
    bid = (bid & 7) * 64 + (bid >> 3);           // XCD swizzle, 512 blocks
    const int bx = bid & 15, by = bid >> 4;      // nbx = 1024/64 = 16
    const int tid = threadIdx.x, lane = tid & 63, wid = tid >> 6;
    const int wr = wid >> 1, wc = wid & 1;       // waves 64x32
    const int lr = lane & 15, lg4 = lane >> 4;
    f32x4 acc[4][2];
#pragma unroll
    for (int m = 0; m < 4; ++m)
#pragma unroll
        for (int n = 0; n < 2; ++n) acc[m][n] = (f32x4)0.0f;
    const int srow = lane >> 3;                  // 0..7
    const int csrc = ((lane & 7) ^ srow) * 8;    // pre-swizzled source elems
    for (int k0 = 0; k0 < K; k0 += 64) {
#pragma unroll
        for (int i = 0; i < 4; ++i)
            gl_lds16(A + (size_t)(by*128 + i*32 + wid*8 + srow)*K + k0 + csrc,
                     &As[(i*32 + wid*8)*64]);
#pragma unroll
        for (int j = 0; j < 2; ++j)
            gl_lds16(BT + (size_t)(bx*64 + j*32 + wid*8 + srow)*K + k0 + csrc,
                     &Bs[(j*32 + wid*8)*64]);
        __syncthreads();
        bf16x8 af[4][2], bfr[2][2];
#pragma unroll
        for (int m = 0; m < 4; ++m) {
            int row = wr*64 + m*16 + lr;         // row&7 == lr&7
#pragma unroll
            for (int kk = 0; kk < 2; ++kk)
                af[m][kk] = *(const bf16x8*)&As[row*64 + (((kk*4 + lg4) ^ (lr & 7))*8)];
        }
#pragma unroll
        for (int n = 0; n < 2; ++n) {
            int row = wc*32 + n*16 + lr;         // row&7 == lr&7
#pragma unroll
            for (int kk = 0; kk < 2; ++kk)
                bfr[n][kk] = *(const bf16x8*)&Bs[row*64 + (((kk*4 + lg4) ^ (lr & 7))*8)];
        }
#pragma unroll
        for (int m = 0; m < 4; ++m)
#pragma unroll
            for (int n = 0; n < 2; ++n) {
                acc[m][n] = __builtin_amdgcn_mfma_f32_16x16x32_bf16(af[m][0], bfr[n][0], acc[m][n], 0, 0, 0);
                acc[m][n] = __builtin_amdgcn_mfma_f32_16x16x32_bf16(af[m][1], bfr[n][1], acc[m][n], 0, 0, 0);
            }
        __syncthreads();
    }
    const int crow = by*128 + wr*64;
    const int ccol = bx*64 + wc*32 + lr;
#pragma unroll
    for (int m = 0; m < 4; ++m)
#pragma unroll
        for (int r = 0; r < 4; ++r) {
            int row = crow + m*16 + lg4*4 + r;
#pragma unroll
            for (int n = 0; n < 2; ++n)
                C[(size_t)row*N + ccol + n*16] = acc[m][n][r];
        }
}

// ---- decay attention: QBLK=128, dbuf prefetch, decay-reach jt skip ----
__global__ __launch_bounds__(256) void attn_kernel(
    const bf16* __restrict__ qh, const bf16* __restrict__ ql,
    const bf16* __restrict__ kh, const bf16* __restrict__ kl,
    const bf16* __restrict__ vt, const double* __restrict__ cl,
    const bf16* __restrict__ Gf, const float* __restrict__ rms_w,
    bf16* __restrict__ Y) {
    __shared__ __align__(16) bf16 Ksh[2][64*64];  // [key][d] swizzled, ping-pong
    __shared__ __align__(16) bf16 Ksl[2][64*64];
    __shared__ __align__(16) bf16 Vs[2][64*64];   // [d][key] swizzled, ping-pong
    __shared__ __align__(16) bf16 Ps[128*64];     // [qrow][key] swizzled
    const int rank = blockIdx.x >> 5, bh = blockIdx.x & 31;
    const int it = (rank < 8) ? (15 - rank) : (rank - 8);
    const int b = bh >> 4, h = bh & 15;
    const int tid = threadIdx.x, lane = tid & 63, wid = tid >> 6;
    const int i0 = it * 128;
    const int lr = lane & 15, lg4 = lane >> 4;
    bf16x8 qfh[2][2], qfl[2][2];
#pragma unroll
    for (int mm = 0; mm < 2; ++mm) {
        int qtok = i0 + wid*32 + mm*16 + lr;
        size_t qa = (size_t)(b*T_ + qtok)*E_ + h*64 + lg4*8;
        qfh[mm][0] = *(const bf16x8*)(qh + qa);
        qfh[mm][1] = *(const bf16x8*)(qh + qa + 32);
        qfl[mm][0] = *(const bf16x8*)(ql + qa);
        qfl[mm][1] = *(const bf16x8*)(ql + qa + 32);
    }
    const double* clrow = cl + (size_t)bh*T_;
    const double base = clrow[i0];
    float cli2[2][4];
#pragma unroll
    for (int mm = 0; mm < 2; ++mm)
#pragma unroll
        for (int r = 0; r < 4; ++r)
            cli2[mm][r] = (float)(clrow[i0 + wid*32 + mm*16 + lg4*4 + r] - base);
    f32x4 oacc[2][4];
#pragma unroll
    for (int mm = 0; mm < 2; ++mm)
#pragma unroll
        for (int n = 0; n < 4; ++n) oacc[mm][n] = (f32x4)0.0f;
    const int srow8 = lane >> 3;
    const int csrc  = (lane & 7) ^ srow8;
    auto STAGE = [&](int jt, int buf) {
        const int j0 = jt * 64;
#pragma unroll
        for (int i = 0; i < 2; ++i) {
            int krow = j0 + i*32 + wid*8 + srow8;
            int drow = i*32 + wid*8 + srow8;
            size_t gk = (size_t)(b*T_ + krow)*E_ + h*64 + csrc*8;
            gl_lds16(kh + gk, &Ksh[buf][(i*32 + wid*8)*64]);
            gl_lds16(kl + gk, &Ksl[buf][(i*32 + wid*8)*64]);
            gl_lds16(vt + (size_t)(bh*64 + drow)*T_ + j0 + csrc*8, &Vs[buf][(i*32 + wid*8)*64]);
        }
    };
    const int niter = 2*it + 2;
    int jt_min;
    {
        int lo = 0, hi = niter - 1;
        while (lo < hi) {
            int mid = (lo + hi) >> 1;
            int jend = mid*64 + 63; if (jend > i0) jend = i0;
            if (clrow[jend] <= base + 95.0) hi = mid; else lo = mid + 1;
        }
        jt_min = lo;
    }
    STAGE(jt_min, 0);
    __syncthreads();
    int cur = 0;
    for (int jt = jt_min; jt < niter; ++jt) {
        const int j0 = jt * 64;
        if (jt + 1 < niter) STAGE(jt + 1, cur ^ 1);
#pragma unroll
        for (int n = 0; n < 4; ++n) {
            const int r = n*16 + lr;
            const int sw = r & 7;
            const int ko = r*64;
            bf16x8 k_h0 = *(const bf16x8*)&Ksh[cur][ko + ((lg4 ^ sw)*8)];
            bf16x8 k_h1 = *(const bf16x8*)&Ksh[cur][ko + (((lg4+4) ^ sw)*8)];
            bf16x8 k_l0 = *(const bf16x8*)&Ksl[cur][ko + ((lg4 ^ sw)*8)];
            bf16x8 k_l1 = *(const bf16x8*)&Ksl[cur][ko + (((lg4+4) ^ sw)*8)];
            const int j = j0 + r;
            const float cj = (float)(clrow[j] - base);
#pragma unroll
            for (int mm = 0; mm < 2; ++mm) {
                f32x4 s = (f32x4)0.0f;
                __builtin_amdgcn_s_setprio(1);
                s = __builtin_amdgcn_mfma_f32_16x16x32_bf16(qfl[mm][0], k_h0, s, 0, 0, 0);
                s = __builtin_amdgcn_mfma_f32_16x16x32_bf16(qfl[mm][1], k_h1, s, 0, 0, 0);
                s = __builtin_amdgcn_mfma_f32_16x16x32_bf16(qfh[mm][0], k_l0, s, 0, 0, 0);
                s = __builtin_amdgcn_mfma_f32_16x16x32_bf16(qfh[mm][1], k_l1, s, 0, 0, 0);
                s = __builtin_amdgcn_mfma_f32_16x16x32_bf16(qfh[mm][0], k_h0, s, 0, 0, 0);
                s = __builtin_amdgcn_mfma_f32_16x16x32_bf16(qfh[mm][1], k_h1, s, 0, 0, 0);
                __builtin_amdgcn_s_setprio(0);
                const int prbase = wid*32 + mm*16 + lg4*4;
#pragma unroll
                for (int r4 = 0; r4 < 4; ++r4) {
                    const int pr = prbase + r4;
                    const int qrow = i0 + pr;
                    float val = (j <= qrow)
                        ? s[r4] * __expf(cli2[mm][r4] - cj) : 0.0f;
                    const int cw = n*2 + (lr >> 3);
                    Ps[pr*64 + ((cw ^ (pr & 7))*8) + (lane & 7)] = (bf16)val;
                }
            }
        }
#pragma unroll
        for (int kk = 0; kk < 2; ++kk) {
            const int js = kk*4 + lg4;
            bf16x8 pf[2];
#pragma unroll
            for (int mm = 0; mm < 2; ++mm) {
                const int rp = wid*32 + mm*16 + lr;
                pf[mm] = *(const bf16x8*)&Ps[rp*64 + ((js ^ (rp & 7))*8)];
            }
            __builtin_amdgcn_s_setprio(1);
#pragma unroll
            for (int n = 0; n < 4; ++n) {
                const int rv = n*16 + lr;
                bf16x8 vf = *(const bf16x8*)&Vs[cur][rv*64 + ((js ^ (rv & 7))*8)];
                oacc[0][n] = __builtin_amdgcn_mfma_f32_16x16x32_bf16(pf[0], vf, oacc[0][n], 0, 0, 0);
                oacc[1][n] = __builtin_amdgcn_mfma_f32_16x16x32_bf16(pf[1], vf, oacc[1][n], 0, 0, 0);
            }
            __builtin_amdgcn_s_setprio(0);
        }
        __syncthreads();
        cur ^= 1;
    }
#pragma unroll
    for (int mm = 0; mm < 2; ++mm)
#pragma unroll
        for (int r = 0; r < 4; ++r) {
            float ss = oacc[mm][0][r]*oacc[mm][0][r] + oacc[mm][1][r]*oacc[mm][1][r]
                     + oacc[mm][2][r]*oacc[mm][2][r] + oacc[mm][3][r]*oacc[mm][3][r];
#pragma unroll
            for (int off = 1; off < 16; off <<= 1) ss += __shfl_xor(ss, off, 64);
            const float scale = rsqrtf(ss * (1.0f/64.0f) + 1e-6f);
            const int gtok = b*T_ + i0 + wid*32 + mm*16 + lg4*4 + r;
#pragma unroll
            for (int n = 0; n < 4; ++n) {
                const int d = n*16 + lr;
                float o = oacc[mm][n][r] * scale * rms_w[d];
                float gate = (float)Gf[(size_t)gtok*E_ + h*64 + d];
                Y[(size_t)gtok*E_ + h*64 + d] = (bf16)(o * gate);
            }
        }
}

extern "C" void kernel_launch(void* const* d_in, const int* in_sizes, int n_in,
                              void* d_out, int out_size, void* d_ws, size_t ws_size,
                              hipStream_t stream) {
    const float* x       = (const float*)d_in[0];
    const float* Wq      = (const float*)d_in[1];
    const float* Wk      = (const float*)d_in[2];
    const float* Wv      = (const float*)d_in[3];
    const float* Wa      = (const float*)d_in[4];
    const float* Wg      = (const float*)d_in[5];
    const float* Wo      = (const float*)d_in[6];
    const float* A_log   = (const float*)d_in[7];
    const float* dt_bias = (const float*)d_in[8];
    const float* rms_w   = (const float*)d_in[9];
    float* out = (float*)d_out;

    char* w = (char*)d_ws;
    size_t off = 0;
    auto alloc = [&](size_t bytes) {
        void* p = w + off; off += (bytes + 255) & ~(size_t)255; return p;
    };
    bf16*   xh   = (bf16*)  alloc((size_t)MTOK*E_*2);
    bf16*   xl   = (bf16*)  alloc((size_t)MTOK*E_*2);
    bf16*   WTqh = (bf16*)  alloc((size_t)2048*E_*2);
    bf16*   WTql = (bf16*)  alloc((size_t)2048*E_*2);
    bf16*   WTvg = (bf16*)  alloc((size_t)2048*E_*2);
    bf16*   WTo  = (bf16*)  alloc((size_t)E_*E_*2);
    bf16*   qhb  = (bf16*)  alloc((size_t)MTOK*E_*2);
    bf16*   qlb  = (bf16*)  alloc((size_t)MTOK*E_*2);
    bf16*   khb  = (bf16*)  alloc((size_t)MTOK*E_*2);
    bf16*   klb  = (bf16*)  alloc((size_t)MTOK*E_*2);
    bf16*   vt   = (bf16*)  alloc((size_t)MTOK*E_*2);
    bf16*   Gf   = (bf16*)  alloc((size_t)MTOK*E_*2);
    float*  lg   = (float*) alloc((size_t)B_*H_*T_*4);
    double* cl   = (double*)alloc((size_t)B_*H_*T_*8);
    bf16*   Yb   = (bf16*)  alloc((size_t)MTOK*E_*2);

    // merged weight prep + dt + x-split (independent branches, one launch)
    hipLaunchKernelGGL(prep_dtx_kernel, dim3(1536), dim3(256), 0, stream,
                       Wq, Wk, Wv, Wg, Wo, Wa, x, A_log, dt_bias,
                       WTqh, WTql, WTvg, WTo, lg, xh, xl);

    // fused projection GEMMs + scan (blocks >=512)
    hipLaunchKernelGGL(gemm_qkvg_kernel, dim3(544), dim3(256), 0, stream,
                       xh, xl, WTqh, WTql, WTvg, qhb, qlb, khb, klb, vt, Gf, lg, cl);

    // attention + RMSNorm + gate
    hipLaunchKernelGGL(attn_kernel, dim3(512), dim3(256), 0, stream,
                       qhb, qlb, khb, klb, vt, cl, Gf, rms_w, Yb);

    // output projection (BK=64)
    hipLaunchKernelGGL(gemm_out_kernel, dim3(512), dim3(256), 0, stream, Yb, WTo, out);
}